// Round 2
// baseline (552.945 us; speedup 1.0000x reference)
//
#include <hip/hip_runtime.h>

#define T_SEQ 2048
#define CDIM  2048
#define NH    32
#define NG    8
#define HS    64
#define NQKV  3072      // (NH + 2*NG) * HS
#define MROWS 4096      // B * T
#define BATCH 2

typedef __bf16          bf16x8  __attribute__((ext_vector_type(8)));
typedef float           f32x4   __attribute__((ext_vector_type(4)));
typedef unsigned short  ushortx8 __attribute__((ext_vector_type(8)));
typedef unsigned short  ushortx4 __attribute__((ext_vector_type(4)));

__device__ __forceinline__ unsigned short f2bf(float f) {
    unsigned int u = __float_as_uint(f);
    u += 0x7fffu + ((u >> 16) & 1u);          // round-to-nearest-even
    return (unsigned short)(u >> 16);
}
__device__ __forceinline__ float bf2f(unsigned short h) {
    return __uint_as_float(((unsigned int)h) << 16);
}
__device__ __forceinline__ bf16x8 as_bf(ushortx8 u) {
    return __builtin_bit_cast(bf16x8, u);
}

// ---------------------------------------------------------------- converts
__global__ void f2bf_vec(const float* __restrict__ in, unsigned short* __restrict__ out, int n4) {
    int i = blockIdx.x * blockDim.x + threadIdx.x;
    if (i < n4) {
        float4 v = ((const float4*)in)[i];
        ushortx4 o;
        o[0] = f2bf(v.x); o[1] = f2bf(v.y); o[2] = f2bf(v.z); o[3] = f2bf(v.w);
        ((ushortx4*)out)[i] = o;
    }
}

// ---------------------------------------------------------------- GEMM  C = A * Bt^T (+bias)
// A: [M][K] bf16 row-major. Bt: [N][K] fp32 row-major (weights used directly,
// converted to bf16 in-register during LDS staging -> no weight buffers in ws).
// MODE 0: scatter epilogue into Qb/Kb/Vb per-head layout (bias fused)
// MODE 1: fp32 linear output (bias fused)
template<int MODE>
__global__ __launch_bounds__(256)
void gemm_bt(const unsigned short* __restrict__ A, const float* __restrict__ Bt,
             const float* __restrict__ bias, int M, int N, int K,
             float* __restrict__ Cout,
             unsigned short* __restrict__ Qb, unsigned short* __restrict__ Kb,
             unsigned short* __restrict__ Vb) {
    const int tid  = threadIdx.x;
    const int lane = tid & 63, w = tid >> 6;
    const int grp  = lane >> 4, cc = lane & 15;
    const int wm   = w >> 1, wn = w & 1;
    const int m0   = blockIdx.y * 128, n0 = blockIdx.x * 128;

    __shared__ unsigned short Al[128 * 48];
    __shared__ unsigned short Bl[128 * 48];

    f32x4 acc[4][4];
#pragma unroll
    for (int i = 0; i < 4; i++)
#pragma unroll
        for (int j = 0; j < 4; j++) acc[i][j] = (f32x4)0.0f;

    const int r0 = tid >> 2;            // 0..63
    const int k8 = (tid & 3) * 8;       // 0,8,16,24

    for (int k0 = 0; k0 < K; k0 += 32) {
        ushortx8 av0 = *(const ushortx8*)(A + (long)(m0 + r0)      * K + k0 + k8);
        ushortx8 av1 = *(const ushortx8*)(A + (long)(m0 + 64 + r0) * K + k0 + k8);
        const float* bp0 = Bt + (long)(n0 + r0)      * K + k0 + k8;
        const float* bp1 = Bt + (long)(n0 + 64 + r0) * K + k0 + k8;
        float4 b0a = *(const float4*)bp0, b0b = *(const float4*)(bp0 + 4);
        float4 b1a = *(const float4*)bp1, b1b = *(const float4*)(bp1 + 4);
        ushortx8 bv0, bv1;
        bv0[0] = f2bf(b0a.x); bv0[1] = f2bf(b0a.y); bv0[2] = f2bf(b0a.z); bv0[3] = f2bf(b0a.w);
        bv0[4] = f2bf(b0b.x); bv0[5] = f2bf(b0b.y); bv0[6] = f2bf(b0b.z); bv0[7] = f2bf(b0b.w);
        bv1[0] = f2bf(b1a.x); bv1[1] = f2bf(b1a.y); bv1[2] = f2bf(b1a.z); bv1[3] = f2bf(b1a.w);
        bv1[4] = f2bf(b1b.x); bv1[5] = f2bf(b1b.y); bv1[6] = f2bf(b1b.z); bv1[7] = f2bf(b1b.w);
        __syncthreads();
        *(ushortx8*)(Al + r0 * 48 + k8)        = av0;
        *(ushortx8*)(Al + (64 + r0) * 48 + k8) = av1;
        *(ushortx8*)(Bl + r0 * 48 + k8)        = bv0;
        *(ushortx8*)(Bl + (64 + r0) * 48 + k8) = bv1;
        __syncthreads();

        bf16x8 af[4], bfr[4];
#pragma unroll
        for (int mi = 0; mi < 4; mi++)
            af[mi] = as_bf(*(ushortx8*)(Al + (wm * 64 + mi * 16 + cc) * 48 + grp * 8));
#pragma unroll
        for (int ni = 0; ni < 4; ni++)
            bfr[ni] = as_bf(*(ushortx8*)(Bl + (wn * 64 + ni * 16 + cc) * 48 + grp * 8));
#pragma unroll
        for (int mi = 0; mi < 4; mi++)
#pragma unroll
            for (int ni = 0; ni < 4; ni++)
                acc[mi][ni] = __builtin_amdgcn_mfma_f32_16x16x32_bf16(af[mi], bfr[ni], acc[mi][ni], 0, 0, 0);
    }

    if (MODE == 1) {
#pragma unroll
        for (int ni = 0; ni < 4; ni++) {
            const int col = n0 + wn * 64 + ni * 16 + cc;
            const float bb = bias[col];
#pragma unroll
            for (int mi = 0; mi < 4; mi++) {
                const int row = m0 + wm * 64 + mi * 16 + grp * 4;
#pragma unroll
                for (int j = 0; j < 4; j++)
                    Cout[(long)(row + j) * N + col] = acc[mi][ni][j] + bb;
            }
        }
    } else {
        const int slot = (n0 + wn * 64) >> 6;   // 0..47 ; all 64 wave cols share (g,s)
        const int g = slot / 6, s = slot % 6;
        const int b = m0 >> 11;                 // m0 / T_SEQ
        const int t0 = (m0 & (T_SEQ - 1)) + wm * 64;
        unsigned short* dst;
        if (s < 4)        dst = Qb + (long)((b * NH + g * 4 + s) * T_SEQ) * HS;
        else if (s == 4)  dst = Kb + (long)((b * NG + g) * T_SEQ) * HS;
        else              dst = Vb + (long)((b * NG + g) * T_SEQ) * HS;
#pragma unroll
        for (int ni = 0; ni < 4; ni++) {
            const int d = ni * 16 + cc;
            const float bb = bias[slot * 64 + d];
#pragma unroll
            for (int mi = 0; mi < 4; mi++) {
                const int t = t0 + mi * 16 + grp * 4;
#pragma unroll
                for (int j = 0; j < 4; j++)
                    dst[(long)(t + j) * HS + d] = f2bf(acc[mi][ni][j] + bb);
            }
        }
    }
}

// ---------------------------------------------------------------- RoPE (in place, Q gets softmax-scale folded)
__global__ void rope_kernel(unsigned short* __restrict__ Qb, unsigned short* __restrict__ Kb,
                            const float* __restrict__ cosT, const float* __restrict__ sinT) {
    const float QSC = 0.125f * 1.44269504088896340736f;   // 1/sqrt(64) * log2(e)
    long idx = (long)blockIdx.x * blockDim.x + threadIdx.x;
    const long NQP = (long)BATCH * NH * T_SEQ * 32;
    const long NKP = (long)BATCH * NG * T_SEQ * 32;
    unsigned short* base; float sc; long r; int dp;
    if (idx < NQP)            { base = Qb; sc = QSC;  r = idx >> 5;          dp = (int)(idx & 31); }
    else if (idx < NQP + NKP) { long k = idx - NQP; base = Kb; sc = 1.0f; r = k >> 5; dp = (int)(k & 31); }
    else return;
    const int t = (int)(r & (T_SEQ - 1));
    unsigned short* p = base + r * 64;
    float x1 = bf2f(p[dp]), x2 = bf2f(p[dp + 32]);
    float cv = cosT[t * 64 + dp], sv = sinT[t * 64 + dp];
    p[dp]      = f2bf((x1 * cv - x2 * sv) * sc);
    p[dp + 32] = f2bf((x2 * cv + x1 * sv) * sc);
}

// ---------------------------------------------------------------- flash attention (causal, GQA)
// grid: (T/64, NH, B), block: 256. Wave w owns 16 q-rows. KV tile = 64.
__global__ __launch_bounds__(256)
void attn_kernel(const unsigned short* __restrict__ Qb, const unsigned short* __restrict__ Kb,
                 const unsigned short* __restrict__ Vb, unsigned short* __restrict__ Yb) {
    const int qt = blockIdx.x, h = blockIdx.y, b = blockIdx.z;
    const int tid = threadIdx.x, lane = tid & 63, w = tid >> 6;
    const int grp = lane >> 4, cc = lane & 15;
    const int g = h >> 2;
    const unsigned short* Qh = Qb + (long)((b * NH + h) * T_SEQ) * HS;
    const unsigned short* Kh = Kb + (long)((b * NG + g) * T_SEQ) * HS;
    const unsigned short* Vh = Vb + (long)((b * NG + g) * T_SEQ) * HS;
    const int q0 = qt * 64;
    const int qr = q0 + w * 16;

    bf16x8 aq[2];
    aq[0] = as_bf(*(const ushortx8*)(Qh + (long)(qr + cc) * HS + grp * 8));
    aq[1] = as_bf(*(const ushortx8*)(Qh + (long)(qr + cc) * HS + grp * 8 + 32));

    __shared__ unsigned short Vl[64 * 68];     // stride 68: spreads scalar-read banks
    __shared__ unsigned short Pl[4][16 * 72];  // per-wave P, stride 72 keeps b128 reads aligned

    f32x4 o[4];
#pragma unroll
    for (int i = 0; i < 4; i++) o[i] = (f32x4)0.0f;
    float mr[4], lr[4];
#pragma unroll
    for (int j = 0; j < 4; j++) { mr[j] = -1e30f; lr[j] = 0.0f; }

    const int vrow0 = tid >> 3, vcol0 = (tid & 7) * 8;

    for (int kt = 0; kt <= qt; kt++) {
        const int kv0 = kt * 64;
        ushortx8 v0 = *(const ushortx8*)(Vh + (long)(kv0 + vrow0) * HS + vcol0);
        ushortx8 v1 = *(const ushortx8*)(Vh + (long)(kv0 + 32 + vrow0) * HS + vcol0);
        __syncthreads();   // prior tile's V reads done
        *(ushortx4*)(Vl + vrow0 * 68 + vcol0)            = __builtin_shufflevector(v0, v0, 0, 1, 2, 3);
        *(ushortx4*)(Vl + vrow0 * 68 + vcol0 + 4)        = __builtin_shufflevector(v0, v0, 4, 5, 6, 7);
        *(ushortx4*)(Vl + (32 + vrow0) * 68 + vcol0)     = __builtin_shufflevector(v1, v1, 0, 1, 2, 3);
        *(ushortx4*)(Vl + (32 + vrow0) * 68 + vcol0 + 4) = __builtin_shufflevector(v1, v1, 4, 5, 6, 7);
        __syncthreads();

        // S = Q K^T  (scale already folded into Q, exp2 domain)
        f32x4 s[4];
#pragma unroll
        for (int ct = 0; ct < 4; ct++) {
            f32x4 a = (f32x4)0.0f;
            const unsigned short* kp = Kh + (long)(kv0 + ct * 16 + cc) * HS + grp * 8;
            a = __builtin_amdgcn_mfma_f32_16x16x32_bf16(aq[0], as_bf(*(const ushortx8*)kp),        a, 0, 0, 0);
            a = __builtin_amdgcn_mfma_f32_16x16x32_bf16(aq[1], as_bf(*(const ushortx8*)(kp + 32)), a, 0, 0, 0);
            s[ct] = a;
        }
        if (kt == qt) {
#pragma unroll
            for (int ct = 0; ct < 4; ct++)
#pragma unroll
                for (int j = 0; j < 4; j++) {
                    int col = kv0 + ct * 16 + cc, row = qr + grp * 4 + j;
                    if (col > row) s[ct][j] = -1e30f;
                }
        }
        // wave-parallel online softmax (rows live in 16-lane groups)
        float al[4];
#pragma unroll
        for (int j = 0; j < 4; j++) {
            float v = fmaxf(fmaxf(s[0][j], s[1][j]), fmaxf(s[2][j], s[3][j]));
            v = fmaxf(v, __shfl_xor(v, 1));
            v = fmaxf(v, __shfl_xor(v, 2));
            v = fmaxf(v, __shfl_xor(v, 4));
            v = fmaxf(v, __shfl_xor(v, 8));
            float mn = fmaxf(mr[j], v);
            al[j] = exp2f(mr[j] - mn);
            mr[j] = mn;
        }
        float rs[4] = {0.f, 0.f, 0.f, 0.f};
#pragma unroll
        for (int ct = 0; ct < 4; ct++)
#pragma unroll
            for (int j = 0; j < 4; j++) {
                float p = exp2f(s[ct][j] - mr[j]);
                s[ct][j] = p; rs[j] += p;
            }
#pragma unroll
        for (int j = 0; j < 4; j++) {
            float v = rs[j];
            v += __shfl_xor(v, 1); v += __shfl_xor(v, 2);
            v += __shfl_xor(v, 4); v += __shfl_xor(v, 8);
            lr[j] = lr[j] * al[j] + v;
        }
#pragma unroll
        for (int dt = 0; dt < 4; dt++)
#pragma unroll
            for (int j = 0; j < 4; j++) o[dt][j] *= al[j];

        // P -> LDS (bf16), re-read in A-fragment layout (same-wave DS ordering is safe)
#pragma unroll
        for (int ct = 0; ct < 4; ct++)
#pragma unroll
            for (int j = 0; j < 4; j++)
                Pl[w][(grp * 4 + j) * 72 + ct * 16 + cc] = f2bf(s[ct][j]);
        bf16x8 pa[2];
        pa[0] = as_bf(*(ushortx8*)(&Pl[w][cc * 72 + grp * 8]));
        pa[1] = as_bf(*(ushortx8*)(&Pl[w][cc * 72 + grp * 8 + 32]));

        // O += P V
#pragma unroll
        for (int dt = 0; dt < 4; dt++) {
#pragma unroll
            for (int kc = 0; kc < 2; kc++) {
                const int kbase = kc * 32 + grp * 8;
                ushortx8 bv;
#pragma unroll
                for (int jj = 0; jj < 8; jj++)
                    bv[jj] = Vl[(kbase + jj) * 68 + dt * 16 + cc];
                o[dt] = __builtin_amdgcn_mfma_f32_16x16x32_bf16(pa[kc], as_bf(bv), o[dt], 0, 0, 0);
            }
        }
    }

#pragma unroll
    for (int dt = 0; dt < 4; dt++)
#pragma unroll
        for (int j = 0; j < 4; j++) {
            int t = qr + grp * 4 + j;
            float val = o[dt][j] / lr[j];
            Yb[((long)(b * T_SEQ + t)) * CDIM + h * HS + dt * 16 + cc] = f2bf(val);
        }
}

// ---------------------------------------------------------------- launch
// Workspace budget: 40 MB total (was 76 MB -> overran ws_size and corrupted
// the harness's adjacent pristine-input copies; first call passed, replays
// diverged). Layout:
//   XY : 16 MB  @ 0      (x as bf16 for QKV GEMM; reused as attention-out Y)
//   Qb : 16 MB  @ 16 MB
//   Kb :  4 MB  @ 32 MB
//   Vb :  4 MB  @ 36 MB
// Weights are no longer staged in ws: GEMMs read fp32 weights directly and
// convert during LDS staging.
extern "C" void kernel_launch(void* const* d_in, const int* in_sizes, int n_in,
                              void* d_out, int out_size, void* d_ws, size_t ws_size,
                              hipStream_t stream) {
    const float* x      = (const float*)d_in[0];
    const float* cosT   = (const float*)d_in[1];
    const float* sinT   = (const float*)d_in[2];
    const float* attn_w = (const float*)d_in[3];
    const float* attn_b = (const float*)d_in[4];
    const float* proj_w = (const float*)d_in[5];
    const float* proj_b = (const float*)d_in[6];
    float* out = (float*)d_out;

    char* p = (char*)d_ws;
    unsigned short* XY = (unsigned short*)p; p += (size_t)MROWS * CDIM * 2;           // 16 MB
    unsigned short* Qb = (unsigned short*)p; p += (size_t)BATCH * NH * T_SEQ * HS * 2; // 16 MB
    unsigned short* Kb = (unsigned short*)p; p += (size_t)BATCH * NG * T_SEQ * HS * 2; //  4 MB
    unsigned short* Vb = (unsigned short*)p; p += (size_t)BATCH * NG * T_SEQ * HS * 2; //  4 MB

    // 1) convert x -> bf16
    f2bf_vec<<<(MROWS * CDIM / 4 + 255) / 256, 256, 0, stream>>>(x, XY, MROWS * CDIM / 4);

    // 2) QKV GEMM (+bias) -> per-head Q/K/V, weights read as fp32 directly
    gemm_bt<0><<<dim3(NQKV / 128, MROWS / 128), 256, 0, stream>>>(
        XY, attn_w, attn_b, MROWS, NQKV, CDIM, nullptr, Qb, Kb, Vb);

    // 3) RoPE in place (Q also gets 0.125*log2e folded)
    {
        long npairs = (long)BATCH * NH * T_SEQ * 32 + (long)BATCH * NG * T_SEQ * 32;
        rope_kernel<<<(int)((npairs + 255) / 256), 256, 0, stream>>>(Qb, Kb, cosT, sinT);
    }

    // 4) flash attention -> Y (reuses XY region; x-bf16 is dead now)
    attn_kernel<<<dim3(T_SEQ / 64, NH, BATCH), 256, 0, stream>>>(Qb, Kb, Vb, XY);

    // 5) out proj (+bias) -> fp32 out
    gemm_bt<1><<<dim3(CDIM / 128, MROWS / 128), 256, 0, stream>>>(
        XY, proj_w, proj_b, MROWS, CDIM, CDIM, out, nullptr, nullptr, nullptr);
}

// Round 4
// 445.049 us; speedup vs baseline: 1.2424x; 1.2424x over previous
//
#include <hip/hip_runtime.h>

#define T_SEQ 2048
#define CDIM  2048
#define NH    32
#define NG    8
#define HS    64
#define NQKV  3072      // (NH + 2*NG) * HS
#define MROWS 4096      // B * T
#define BATCH 2

typedef __bf16          bf16x8  __attribute__((ext_vector_type(8)));
typedef float           f32x4   __attribute__((ext_vector_type(4)));
typedef unsigned short  ushortx8 __attribute__((ext_vector_type(8)));
typedef unsigned short  ushortx4 __attribute__((ext_vector_type(4)));

__device__ __forceinline__ unsigned short f2bf(float f) {
    unsigned int u = __float_as_uint(f);
    u += 0x7fffu + ((u >> 16) & 1u);          // round-to-nearest-even
    return (unsigned short)(u >> 16);
}
__device__ __forceinline__ float bf2f(unsigned short h) {
    return __uint_as_float(((unsigned int)h) << 16);
}
__device__ __forceinline__ bf16x8 as_bf(ushortx8 u) {
    return __builtin_bit_cast(bf16x8, u);
}
// Async global->LDS, 16B per lane. LDS dest = wave-uniform base + lane*16;
// global source is per-lane (m173) -> swizzled layouts via pre-swizzled source.
__device__ __forceinline__ void gload16(const void* g, void* l) {
    __builtin_amdgcn_global_load_lds(
        (const __attribute__((address_space(1))) unsigned int*)g,
        (__attribute__((address_space(3))) unsigned int*)l, 16, 0, 0);
}

// ---------------------------------------------------------------- converts
__global__ void f2bf_vec(const float* __restrict__ in, unsigned short* __restrict__ out, int n4) {
    int i = blockIdx.x * blockDim.x + threadIdx.x;
    if (i < n4) {
        float4 v = ((const float4*)in)[i];
        ushortx4 o;
        o[0] = f2bf(v.x); o[1] = f2bf(v.y); o[2] = f2bf(v.z); o[3] = f2bf(v.w);
        ((ushortx4*)out)[i] = o;
    }
}

// ---------------------------------------------------------------- GEMM  C = A * Bt^T (+bias)
// A: [M][K] bf16 row-major. Bt: [N][K] fp32 row-major (weights used directly).
// MODE 0: scatter epilogue into Qb/Kb/Vb per-head layout (bias fused)
// MODE 1: fp32 linear output (bias fused)
template<int MODE>
__global__ __launch_bounds__(256)
void gemm_bt(const unsigned short* __restrict__ A, const float* __restrict__ Bt,
             const float* __restrict__ bias, int M, int N, int K,
             float* __restrict__ Cout,
             unsigned short* __restrict__ Qb, unsigned short* __restrict__ Kb,
             unsigned short* __restrict__ Vb) {
    const int tid  = threadIdx.x;
    const int lane = tid & 63, w = tid >> 6;
    const int grp  = lane >> 4, cc = lane & 15;
    const int wm   = w >> 1, wn = w & 1;
    const int m0   = blockIdx.y * 128, n0 = blockIdx.x * 128;

    __shared__ unsigned short Al[128 * 48];
    __shared__ unsigned short Bl[128 * 48];

    f32x4 acc[4][4];
#pragma unroll
    for (int i = 0; i < 4; i++)
#pragma unroll
        for (int j = 0; j < 4; j++) acc[i][j] = (f32x4)0.0f;

    const int r0 = tid >> 2;            // 0..63
    const int k8 = (tid & 3) * 8;       // 0,8,16,24

    for (int k0 = 0; k0 < K; k0 += 32) {
        ushortx8 av0 = *(const ushortx8*)(A + (long)(m0 + r0)      * K + k0 + k8);
        ushortx8 av1 = *(const ushortx8*)(A + (long)(m0 + 64 + r0) * K + k0 + k8);
        const float* bp0 = Bt + (long)(n0 + r0)      * K + k0 + k8;
        const float* bp1 = Bt + (long)(n0 + 64 + r0) * K + k0 + k8;
        float4 b0a = *(const float4*)bp0, b0b = *(const float4*)(bp0 + 4);
        float4 b1a = *(const float4*)bp1, b1b = *(const float4*)(bp1 + 4);
        ushortx8 bv0, bv1;
        bv0[0] = f2bf(b0a.x); bv0[1] = f2bf(b0a.y); bv0[2] = f2bf(b0a.z); bv0[3] = f2bf(b0a.w);
        bv0[4] = f2bf(b0b.x); bv0[5] = f2bf(b0b.y); bv0[6] = f2bf(b0b.z); bv0[7] = f2bf(b0b.w);
        bv1[0] = f2bf(b1a.x); bv1[1] = f2bf(b1a.y); bv1[2] = f2bf(b1a.z); bv1[3] = f2bf(b1a.w);
        bv1[4] = f2bf(b1b.x); bv1[5] = f2bf(b1b.y); bv1[6] = f2bf(b1b.z); bv1[7] = f2bf(b1b.w);
        __syncthreads();
        *(ushortx8*)(Al + r0 * 48 + k8)        = av0;
        *(ushortx8*)(Al + (64 + r0) * 48 + k8) = av1;
        *(ushortx8*)(Bl + r0 * 48 + k8)        = bv0;
        *(ushortx8*)(Bl + (64 + r0) * 48 + k8) = bv1;
        __syncthreads();

        bf16x8 af[4], bfr[4];
#pragma unroll
        for (int mi = 0; mi < 4; mi++)
            af[mi] = as_bf(*(ushortx8*)(Al + (wm * 64 + mi * 16 + cc) * 48 + grp * 8));
#pragma unroll
        for (int ni = 0; ni < 4; ni++)
            bfr[ni] = as_bf(*(ushortx8*)(Bl + (wn * 64 + ni * 16 + cc) * 48 + grp * 8));
#pragma unroll
        for (int mi = 0; mi < 4; mi++)
#pragma unroll
            for (int ni = 0; ni < 4; ni++)
                acc[mi][ni] = __builtin_amdgcn_mfma_f32_16x16x32_bf16(af[mi], bfr[ni], acc[mi][ni], 0, 0, 0);
    }

    if (MODE == 1) {
#pragma unroll
        for (int ni = 0; ni < 4; ni++) {
            const int col = n0 + wn * 64 + ni * 16 + cc;
            const float bb = bias[col];
#pragma unroll
            for (int mi = 0; mi < 4; mi++) {
                const int row = m0 + wm * 64 + mi * 16 + grp * 4;
#pragma unroll
                for (int j = 0; j < 4; j++)
                    Cout[(long)(row + j) * N + col] = acc[mi][ni][j] + bb;
            }
        }
    } else {
        const int slot = (n0 + wn * 64) >> 6;   // 0..47 ; all 64 wave cols share (g,s)
        const int g = slot / 6, s = slot % 6;
        const int b = m0 >> 11;                 // m0 / T_SEQ
        const int t0 = (m0 & (T_SEQ - 1)) + wm * 64;
        unsigned short* dst;
        if (s < 4)        dst = Qb + (long)((b * NH + g * 4 + s) * T_SEQ) * HS;
        else if (s == 4)  dst = Kb + (long)((b * NG + g) * T_SEQ) * HS;
        else              dst = Vb + (long)((b * NG + g) * T_SEQ) * HS;
#pragma unroll
        for (int ni = 0; ni < 4; ni++) {
            const int d = ni * 16 + cc;
            const float bb = bias[slot * 64 + d];
#pragma unroll
            for (int mi = 0; mi < 4; mi++) {
                const int t = t0 + mi * 16 + grp * 4;
#pragma unroll
                for (int j = 0; j < 4; j++)
                    dst[(long)(t + j) * HS + d] = f2bf(acc[mi][ni][j] + bb);
            }
        }
    }
}

// ---------------------------------------------------------------- RoPE (in place, Q gets softmax-scale folded)
__global__ void rope_kernel(unsigned short* __restrict__ Qb, unsigned short* __restrict__ Kb,
                            const float* __restrict__ cosT, const float* __restrict__ sinT) {
    const float QSC = 0.125f * 1.44269504088896340736f;   // 1/sqrt(64) * log2(e)
    long idx = (long)blockIdx.x * blockDim.x + threadIdx.x;
    const long NQP = (long)BATCH * NH * T_SEQ * 32;
    const long NKP = (long)BATCH * NG * T_SEQ * 32;
    unsigned short* base; float sc; long r; int dp;
    if (idx < NQP)            { base = Qb; sc = QSC;  r = idx >> 5;          dp = (int)(idx & 31); }
    else if (idx < NQP + NKP) { long k = idx - NQP; base = Kb; sc = 1.0f; r = k >> 5; dp = (int)(k & 31); }
    else return;
    const int t = (int)(r & (T_SEQ - 1));
    unsigned short* p = base + r * 64;
    float x1 = bf2f(p[dp]), x2 = bf2f(p[dp + 32]);
    float cv = cosT[t * 64 + dp], sv = sinT[t * 64 + dp];
    p[dp]      = f2bf((x1 * cv - x2 * sv) * sc);
    p[dp + 32] = f2bf((x2 * cv + x1 * sv) * sc);
}

// ---------------------------------------------------------------- flash attention (causal, GQA)
// 1D grid of 1024 blocks (XCD-swizzled), 256 threads. Block owns 128 q-rows,
// wave owns 32. KV tile 64, double-buffered:
//   K: global_load_lds, unit u of row r holds global chunk u^(r&7) -> XOR-read
//   V: reg-staged TRANSPOSED into Vt[d][kv] (stride 72) -> B-frags are one
//      aligned ds_read_b128 each (no exotic instructions).
__global__ __launch_bounds__(256, 3)
void attn_kernel(const unsigned short* __restrict__ Qb, const unsigned short* __restrict__ Kb,
                 const unsigned short* __restrict__ Vb, unsigned short* __restrict__ Yb) {
    // T1: bijective XCD swizzle (1024 % 8 == 0): each XCD's 128 blocks share
    // 8 (h,b) KV panels (4 MB) -> L2-resident.
    const int dsp = blockIdx.x;
    const int wk  = (dsp & 7) * 128 + (dsp >> 3);
    const int bx  = wk & 15;
    const int h   = (wk >> 4) & 31;
    const int b   = wk >> 9;

    const int tid = threadIdx.x, lane = tid & 63, w = tid >> 6;
    const int grp = lane >> 4, cc = lane & 15;
    const int g = h >> 2;
    const unsigned short* Qh = Qb + (long)((b * NH + h) * T_SEQ) * HS;
    const unsigned short* Kh = Kb + (long)((b * NG + g) * T_SEQ) * HS;
    const unsigned short* Vh = Vb + (long)((b * NG + g) * T_SEQ) * HS;
    const int q0  = bx * 128;
    const int qrb = q0 + w * 32;        // wave's first q-row
    const int NT  = 2 * bx + 2;         // kv tiles for this block

    __shared__ unsigned short Kl[2][4096];      // [64 rows][8 units x 8 elems], unit-XOR layout
    __shared__ unsigned short Vt[2][64 * 72];   // transposed: Vt[d][kv], stride 72
    __shared__ unsigned short Pl[4][32 * 72];   // per-wave P scratch

    // Q fragments (scale/log2e folded by rope): aq[qh][khalf]
    bf16x8 aq[2][2];
#pragma unroll
    for (int qh = 0; qh < 2; qh++)
#pragma unroll
        for (int kh = 0; kh < 2; kh++)
            aq[qh][kh] = as_bf(*(const ushortx8*)(Qh + (long)(qrb + qh * 16 + cc) * HS + kh * 32 + grp * 8));

    // --- K staging geometry: 512 16B units/tile; this thread's two units ---
    const int U0 = (w * 2) * 64 + lane, U1 = U0 + 64;
    const int gk0 = (U0 >> 3) * 64 + (((U0 & 7) ^ ((U0 >> 3) & 7)) * 8);
    const int gk1 = (U1 >> 3) * 64 + (((U1 & 7) ^ ((U1 >> 3) & 7)) * 8);
    const int du0 = (w * 2) * 512, du1 = (w * 2 + 1) * 512;   // wave-uniform LDS elem dests

    // --- V staging geometry: thread owns kv pair 2p,2p+1 and d-chunk 8c..8c+7 ---
    const int vp = tid & 31, vc = tid >> 5;
    const long vsrc = (long)(2 * vp) * HS + 8 * vc;

    f32x4 o[2][4];
#pragma unroll
    for (int qh = 0; qh < 2; qh++)
#pragma unroll
        for (int dt = 0; dt < 4; dt++) o[qh][dt] = (f32x4)0.0f;
    float mr[2][4], lr[2][4];
#pragma unroll
    for (int qh = 0; qh < 2; qh++)
#pragma unroll
        for (int j = 0; j < 4; j++) { mr[qh][j] = -1e30f; lr[qh][j] = 0.0f; }

    // prologue: stage tile 0
    {
        gload16(Kh + gk0, &Kl[0][du0]);
        gload16(Kh + gk1, &Kl[0][du1]);
        ushortx8 v0 = *(const ushortx8*)(Vh + vsrc);
        ushortx8 v1 = *(const ushortx8*)(Vh + vsrc + HS);
#pragma unroll
        for (int e = 0; e < 8; e++) {
            unsigned int pk = (unsigned int)v0[e] | ((unsigned int)v1[e] << 16);
            *(unsigned int*)&Vt[0][(8 * vc + e) * 72 + 2 * vp] = pk;
        }
    }
    __syncthreads();                    // drains vmcnt+lgkm -> tile 0 ready

    for (int t = 0; t < NT; ++t) {
        const int cur = t & 1;
        const bool pre = (t + 1 < NT);
        ushortx8 v0, v1;
        if (pre) {                      // issue next tile's loads early (T14)
            const long kofs = (long)(t + 1) * 64 * HS;
            v0 = *(const ushortx8*)(Vh + kofs + vsrc);
            v1 = *(const ushortx8*)(Vh + kofs + vsrc + HS);
            gload16(Kh + kofs + gk0, &Kl[cur ^ 1][du0]);
            gload16(Kh + kofs + gk1, &Kl[cur ^ 1][du1]);
        }
        const int kv0 = t * 64;
        if (kv0 <= qrb + 31) {          // wave-uniform: skip fully-masked tiles
            // --- QK^T ---
            bf16x8 kf[4][2];
#pragma unroll
            for (int ct = 0; ct < 4; ct++)
#pragma unroll
                for (int kh = 0; kh < 2; kh++)
                    kf[ct][kh] = as_bf(*(const ushortx8*)&Kl[cur][(ct * 16 + cc) * 64 + (((kh * 4 + grp) ^ (cc & 7)) * 8)]);
            f32x4 s[2][4];
            __builtin_amdgcn_s_setprio(1);
#pragma unroll
            for (int qh = 0; qh < 2; qh++)
#pragma unroll
                for (int ct = 0; ct < 4; ct++) {
                    f32x4 a = (f32x4)0.0f;
                    a = __builtin_amdgcn_mfma_f32_16x16x32_bf16(aq[qh][0], kf[ct][0], a, 0, 0, 0);
                    a = __builtin_amdgcn_mfma_f32_16x16x32_bf16(aq[qh][1], kf[ct][1], a, 0, 0, 0);
                    s[qh][ct] = a;
                }
            __builtin_amdgcn_s_setprio(0);
            // --- causal mask ---
            if (kv0 + 63 > qrb) {
#pragma unroll
                for (int qh = 0; qh < 2; qh++)
#pragma unroll
                    for (int ct = 0; ct < 4; ct++)
#pragma unroll
                        for (int j = 0; j < 4; j++) {
                            int col = kv0 + ct * 16 + cc, row = qrb + qh * 16 + grp * 4 + j;
                            if (col > row) s[qh][ct][j] = -1e30f;
                        }
            }
            // --- online softmax (rows in 16-lane groups; exp2 domain) ---
#pragma unroll
            for (int qh = 0; qh < 2; qh++) {
                float al[4];
#pragma unroll
                for (int j = 0; j < 4; j++) {
                    float v = fmaxf(fmaxf(s[qh][0][j], s[qh][1][j]), fmaxf(s[qh][2][j], s[qh][3][j]));
                    v = fmaxf(v, __shfl_xor(v, 1));
                    v = fmaxf(v, __shfl_xor(v, 2));
                    v = fmaxf(v, __shfl_xor(v, 4));
                    v = fmaxf(v, __shfl_xor(v, 8));
                    float mn = fmaxf(mr[qh][j], v);
                    al[j] = exp2f(mr[qh][j] - mn);
                    mr[qh][j] = mn;
                }
                float rs[4] = {0.f, 0.f, 0.f, 0.f};
#pragma unroll
                for (int ct = 0; ct < 4; ct++)
#pragma unroll
                    for (int j = 0; j < 4; j++) {
                        float p = exp2f(s[qh][ct][j] - mr[qh][j]);
                        s[qh][ct][j] = p; rs[j] += p;
                    }
#pragma unroll
                for (int j = 0; j < 4; j++) {
                    float v = rs[j];
                    v += __shfl_xor(v, 1); v += __shfl_xor(v, 2);
                    v += __shfl_xor(v, 4); v += __shfl_xor(v, 8);
                    lr[qh][j] = lr[qh][j] * al[j] + v;
                }
#pragma unroll
                for (int dt = 0; dt < 4; dt++)
#pragma unroll
                    for (int j = 0; j < 4; j++) o[qh][dt][j] *= al[j];
            }
            // --- P -> LDS (bf16), re-read as A-fragments (same-wave ordering) ---
#pragma unroll
            for (int qh = 0; qh < 2; qh++)
#pragma unroll
                for (int ct = 0; ct < 4; ct++)
#pragma unroll
                    for (int j = 0; j < 4; j++)
                        Pl[w][(qh * 16 + grp * 4 + j) * 72 + ct * 16 + cc] = f2bf(s[qh][ct][j]);
            bf16x8 pa[2][2];
#pragma unroll
            for (int qh = 0; qh < 2; qh++)
#pragma unroll
                for (int kc = 0; kc < 2; kc++)
                    pa[qh][kc] = as_bf(*(ushortx8*)&Pl[w][(qh * 16 + cc) * 72 + kc * 32 + grp * 8]);
            // --- O += P V : B-frags from transposed V, one b128 each ---
            __builtin_amdgcn_s_setprio(1);
#pragma unroll
            for (int dt = 0; dt < 4; dt++) {
                bf16x8 vb[2];
#pragma unroll
                for (int kc = 0; kc < 2; kc++)
                    vb[kc] = as_bf(*(const ushortx8*)&Vt[cur][(dt * 16 + cc) * 72 + kc * 32 + grp * 8]);
#pragma unroll
                for (int qh = 0; qh < 2; qh++)
#pragma unroll
                    for (int kc = 0; kc < 2; kc++)
                        o[qh][dt] = __builtin_amdgcn_mfma_f32_16x16x32_bf16(pa[qh][kc], vb[kc], o[qh][dt], 0, 0, 0);
            }
            __builtin_amdgcn_s_setprio(0);
        }
        if (pre) {                      // write next V tile (compiler waits vmcnt on v0/v1)
#pragma unroll
            for (int e = 0; e < 8; e++) {
                unsigned int pk = (unsigned int)v0[e] | ((unsigned int)v1[e] << 16);
                *(unsigned int*)&Vt[cur ^ 1][(8 * vc + e) * 72 + 2 * vp] = pk;
            }
        }
        __syncthreads();                // drains vmcnt (K prefetch) + lgkm; flips buffers
    }

    // epilogue
#pragma unroll
    for (int qh = 0; qh < 2; qh++) {
        float inv[4];
#pragma unroll
        for (int j = 0; j < 4; j++) inv[j] = 1.0f / lr[qh][j];
#pragma unroll
        for (int dt = 0; dt < 4; dt++)
#pragma unroll
            for (int j = 0; j < 4; j++) {
                int row = qrb + qh * 16 + grp * 4 + j;
                Yb[((long)(b * T_SEQ + row)) * CDIM + h * HS + dt * 16 + cc] = f2bf(o[qh][dt][j] * inv[j]);
            }
    }
}

// ---------------------------------------------------------------- launch
// Workspace: 40 MB. XY 16 (x-bf16, reused as attn-out Y) | Qb 16 | Kb 4 | Vb 4.
extern "C" void kernel_launch(void* const* d_in, const int* in_sizes, int n_in,
                              void* d_out, int out_size, void* d_ws, size_t ws_size,
                              hipStream_t stream) {
    const float* x      = (const float*)d_in[0];
    const float* cosT   = (const float*)d_in[1];
    const float* sinT   = (const float*)d_in[2];
    const float* attn_w = (const float*)d_in[3];
    const float* attn_b = (const float*)d_in[4];
    const float* proj_w = (const float*)d_in[5];
    const float* proj_b = (const float*)d_in[6];
    float* out = (float*)d_out;

    char* p = (char*)d_ws;
    unsigned short* XY = (unsigned short*)p; p += (size_t)MROWS * CDIM * 2;            // 16 MB
    unsigned short* Qb = (unsigned short*)p; p += (size_t)BATCH * NH * T_SEQ * HS * 2; // 16 MB
    unsigned short* Kb = (unsigned short*)p; p += (size_t)BATCH * NG * T_SEQ * HS * 2; //  4 MB
    unsigned short* Vb = (unsigned short*)p; p += (size_t)BATCH * NG * T_SEQ * HS * 2; //  4 MB

    // 1) convert x -> bf16
    f2bf_vec<<<(MROWS * CDIM / 4 + 255) / 256, 256, 0, stream>>>(x, XY, MROWS * CDIM / 4);

    // 2) QKV GEMM (+bias) -> per-head Q/K/V
    gemm_bt<0><<<dim3(NQKV / 128, MROWS / 128), 256, 0, stream>>>(
        XY, attn_w, attn_b, MROWS, NQKV, CDIM, nullptr, Qb, Kb, Vb);

    // 3) RoPE in place (Q also gets 0.125*log2e folded)
    {
        long npairs = (long)BATCH * NH * T_SEQ * 32 + (long)BATCH * NG * T_SEQ * 32;
        rope_kernel<<<(int)((npairs + 255) / 256), 256, 0, stream>>>(Qb, Kb, cosT, sinT);
    }

    // 4) flash attention -> Y (reuses XY region)
    attn_kernel<<<dim3((T_SEQ / 128) * NH * BATCH), 256, 0, stream>>>(Qb, Kb, Vb, XY);

    // 5) out proj (+bias) -> fp32 out
    gemm_bt<1><<<dim3(CDIM / 128, MROWS / 128), 256, 0, stream>>>(
        XY, proj_w, proj_b, MROWS, CDIM, CDIM, out, nullptr, nullptr, nullptr);
}

// Round 8
// 399.682 us; speedup vs baseline: 1.3835x; 1.1135x over previous
//
#include <hip/hip_runtime.h>

#define T_SEQ 2048
#define CDIM  2048
#define NH    32
#define NG    8
#define HS    64
#define NQKV  3072      // (NH + 2*NG) * HS
#define MROWS 4096      // B * T
#define BATCH 2

typedef __bf16          bf16x8  __attribute__((ext_vector_type(8)));
typedef float           f32x4   __attribute__((ext_vector_type(4)));
typedef unsigned short  ushortx8 __attribute__((ext_vector_type(8)));
typedef unsigned short  ushortx4 __attribute__((ext_vector_type(4)));

__device__ __forceinline__ unsigned short f2bf(float f) {
    unsigned int u = __float_as_uint(f);
    u += 0x7fffu + ((u >> 16) & 1u);          // round-to-nearest-even
    return (unsigned short)(u >> 16);
}
__device__ __forceinline__ float bf2f(unsigned short h) {
    return __uint_as_float(((unsigned int)h) << 16);
}
__device__ __forceinline__ bf16x8 as_bf(ushortx8 u) {
    return __builtin_bit_cast(bf16x8, u);
}
// Async global->LDS, 16B per lane. LDS dest = wave-uniform base + lane*16;
// global source is per-lane (m173) -> swizzled layouts via pre-swizzled source.
__device__ __forceinline__ void gload16(const void* g, void* l) {
    __builtin_amdgcn_global_load_lds(
        (const __attribute__((address_space(1))) unsigned int*)g,
        (__attribute__((address_space(3))) unsigned int*)l, 16, 0, 0);
}

// ---------------------------------------------------------------- converts
__global__ void f2bf_vec(const float* __restrict__ in, unsigned short* __restrict__ out, int n4) {
    int i = blockIdx.x * blockDim.x + threadIdx.x;
    if (i < n4) {
        float4 v = ((const float4*)in)[i];
        ushortx4 o;
        o[0] = f2bf(v.x); o[1] = f2bf(v.y); o[2] = f2bf(v.z); o[3] = f2bf(v.w);
        ((ushortx4*)out)[i] = o;
    }
}

// ---------------------------------------------------------------- GEMM  C = A * Bt^T (+bias)
// A: [M][K] bf16 row-major. Bt: [N][K] fp32 row-major (weights used directly).
// MODE 0: scatter epilogue into Qb/Kb/Vb per-head layout (bias fused)
// MODE 1: fp32 linear output (bias fused)
template<int MODE>
__global__ __launch_bounds__(256)
void gemm_bt(const unsigned short* __restrict__ A, const float* __restrict__ Bt,
             const float* __restrict__ bias, int M, int N, int K,
             float* __restrict__ Cout,
             unsigned short* __restrict__ Qb, unsigned short* __restrict__ Kb,
             unsigned short* __restrict__ Vb) {
    const int tid  = threadIdx.x;
    const int lane = tid & 63, w = tid >> 6;
    const int grp  = lane >> 4, cc = lane & 15;
    const int wm   = w >> 1, wn = w & 1;
    const int m0   = blockIdx.y * 128, n0 = blockIdx.x * 128;

    __shared__ unsigned short Al[128 * 48];
    __shared__ unsigned short Bl[128 * 48];

    f32x4 acc[4][4];
#pragma unroll
    for (int i = 0; i < 4; i++)
#pragma unroll
        for (int j = 0; j < 4; j++) acc[i][j] = (f32x4)0.0f;

    const int r0 = tid >> 2;            // 0..63
    const int k8 = (tid & 3) * 8;       // 0,8,16,24

    for (int k0 = 0; k0 < K; k0 += 32) {
        ushortx8 av0 = *(const ushortx8*)(A + (long)(m0 + r0)      * K + k0 + k8);
        ushortx8 av1 = *(const ushortx8*)(A + (long)(m0 + 64 + r0) * K + k0 + k8);
        const float* bp0 = Bt + (long)(n0 + r0)      * K + k0 + k8;
        const float* bp1 = Bt + (long)(n0 + 64 + r0) * K + k0 + k8;
        float4 b0a = *(const float4*)bp0, b0b = *(const float4*)(bp0 + 4);
        float4 b1a = *(const float4*)bp1, b1b = *(const float4*)(bp1 + 4);
        ushortx8 bv0, bv1;
        bv0[0] = f2bf(b0a.x); bv0[1] = f2bf(b0a.y); bv0[2] = f2bf(b0a.z); bv0[3] = f2bf(b0a.w);
        bv0[4] = f2bf(b0b.x); bv0[5] = f2bf(b0b.y); bv0[6] = f2bf(b0b.z); bv0[7] = f2bf(b0b.w);
        bv1[0] = f2bf(b1a.x); bv1[1] = f2bf(b1a.y); bv1[2] = f2bf(b1a.z); bv1[3] = f2bf(b1a.w);
        bv1[4] = f2bf(b1b.x); bv1[5] = f2bf(b1b.y); bv1[6] = f2bf(b1b.z); bv1[7] = f2bf(b1b.w);
        __syncthreads();
        *(ushortx8*)(Al + r0 * 48 + k8)        = av0;
        *(ushortx8*)(Al + (64 + r0) * 48 + k8) = av1;
        *(ushortx8*)(Bl + r0 * 48 + k8)        = bv0;
        *(ushortx8*)(Bl + (64 + r0) * 48 + k8) = bv1;
        __syncthreads();

        bf16x8 af[4], bfr[4];
#pragma unroll
        for (int mi = 0; mi < 4; mi++)
            af[mi] = as_bf(*(ushortx8*)(Al + (wm * 64 + mi * 16 + cc) * 48 + grp * 8));
#pragma unroll
        for (int ni = 0; ni < 4; ni++)
            bfr[ni] = as_bf(*(ushortx8*)(Bl + (wn * 64 + ni * 16 + cc) * 48 + grp * 8));
#pragma unroll
        for (int mi = 0; mi < 4; mi++)
#pragma unroll
            for (int ni = 0; ni < 4; ni++)
                acc[mi][ni] = __builtin_amdgcn_mfma_f32_16x16x32_bf16(af[mi], bfr[ni], acc[mi][ni], 0, 0, 0);
    }

    if (MODE == 1) {
#pragma unroll
        for (int ni = 0; ni < 4; ni++) {
            const int col = n0 + wn * 64 + ni * 16 + cc;
            const float bb = bias[col];
#pragma unroll
            for (int mi = 0; mi < 4; mi++) {
                const int row = m0 + wm * 64 + mi * 16 + grp * 4;
#pragma unroll
                for (int j = 0; j < 4; j++)
                    Cout[(long)(row + j) * N + col] = acc[mi][ni][j] + bb;
            }
        }
    } else {
        const int slot = (n0 + wn * 64) >> 6;   // 0..47 ; all 64 wave cols share (g,s)
        const int g = slot / 6, s = slot % 6;
        const int b = m0 >> 11;                 // m0 / T_SEQ
        const int t0 = (m0 & (T_SEQ - 1)) + wm * 64;
        unsigned short* dst;
        if (s < 4)        dst = Qb + (long)((b * NH + g * 4 + s) * T_SEQ) * HS;
        else if (s == 4)  dst = Kb + (long)((b * NG + g) * T_SEQ) * HS;
        else              dst = Vb + (long)((b * NG + g) * T_SEQ) * HS;
#pragma unroll
        for (int ni = 0; ni < 4; ni++) {
            const int d = ni * 16 + cc;
            const float bb = bias[slot * 64 + d];
#pragma unroll
            for (int mi = 0; mi < 4; mi++) {
                const int t = t0 + mi * 16 + grp * 4;
#pragma unroll
                for (int j = 0; j < 4; j++)
                    dst[(long)(t + j) * HS + d] = f2bf(acc[mi][ni][j] + bb);
            }
        }
    }
}

// ---------------------------------------------------------------- RoPE (in place, Q gets softmax-scale folded)
__global__ void rope_kernel(unsigned short* __restrict__ Qb, unsigned short* __restrict__ Kb,
                            const float* __restrict__ cosT, const float* __restrict__ sinT) {
    const float QSC = 0.125f * 1.44269504088896340736f;   // 1/sqrt(64) * log2(e)
    long idx = (long)blockIdx.x * blockDim.x + threadIdx.x;
    const long NQP = (long)BATCH * NH * T_SEQ * 32;
    const long NKP = (long)BATCH * NG * T_SEQ * 32;
    unsigned short* base; float sc; long r; int dp;
    if (idx < NQP)            { base = Qb; sc = QSC;  r = idx >> 5;          dp = (int)(idx & 31); }
    else if (idx < NQP + NKP) { long k = idx - NQP; base = Kb; sc = 1.0f; r = k >> 5; dp = (int)(k & 31); }
    else return;
    const int t = (int)(r & (T_SEQ - 1));
    unsigned short* p = base + r * 64;
    float x1 = bf2f(p[dp]), x2 = bf2f(p[dp + 32]);
    float cv = cosT[t * 64 + dp], sv = sinT[t * 64 + dp];
    p[dp]      = f2bf((x1 * cv - x2 * sv) * sc);
    p[dp + 32] = f2bf((x2 * cv + x1 * sv) * sc);
}

// ---------------------------------------------------------------- flash attention (causal, GQA)
// 512 blocks (XCD-swizzled), 256 threads. Causal work-pairing: block does
// q-tile bx (pass 0) AND q-tile 15-bx (pass 1) -> every block = 36 kv-tiles,
// perfectly balanced, 2 blocks/CU all-resident.
// Wave owns 32 q-rows. KV tile 64, double-buffered:
//   K: global_load_lds, unit u of row r holds global chunk u^(r&7) -> XOR-read
//   V: reg-staged TRANSPOSED into Vt[d][kv] (stride 72); rows 64..79 are a
//      static ones/zeros block so the PV MFMA also computes rowsum(P) -> the
//      softmax denominator comes out of the matrix pipe (no shfl-reduce).
// T13 defer-max: skip max-update + o-rescale while tile max grows <= 8.
// NOTE: Pl stride MUST be >= 64 (P tile is 32x64). Round-5's stride-40 "save"
// overlapped rows -> corrupted P -> zero denominators -> NaN. 72 is the
// round-4-proven stride (144 B rows, 16B-aligned for ds_read_b128).
__global__ __launch_bounds__(256, 3)
void attn_kernel(const unsigned short* __restrict__ Qb, const unsigned short* __restrict__ Kb,
                 const unsigned short* __restrict__ Vb, unsigned short* __restrict__ Yb) {
    // T1: bijective XCD swizzle (512 % 8 == 0)
    const int dsp = blockIdx.x;
    const int wk  = (dsp & 7) * 64 + (dsp >> 3);
    const int bxp = wk & 7;
    const int h   = (wk >> 3) & 31;
    const int b   = wk >> 8;

    const int tid = threadIdx.x, lane = tid & 63, w = tid >> 6;
    const int grp = lane >> 4, cc = lane & 15;
    const int g = h >> 2;
    const unsigned short* Qh = Qb + (long)((b * NH + h) * T_SEQ) * HS;
    const unsigned short* Kh = Kb + (long)((b * NG + g) * T_SEQ) * HS;
    const unsigned short* Vh = Vb + (long)((b * NG + g) * T_SEQ) * HS;

    __shared__ unsigned short Kl[2][4096];      // [64 rows][8 units x 8 elems], unit-XOR layout
    __shared__ unsigned short Vt[2][80 * 72];   // transposed: Vt[d][kv], stride 72; d=64..79 static
    __shared__ unsigned short Pl[4][32 * 72];   // per-wave P scratch (stride 72 >= 64!)

    // ones/zeros rows 64..79 (once; never touched by staging)
    for (int i = tid; i < 2 * 16 * 72; i += 256) {
        int buf = i / (16 * 72), rem = i % (16 * 72);
        int r = rem / 72, c = rem % 72;
        Vt[buf][(64 + r) * 72 + c] = (r == 0) ? (unsigned short)0x3F80 : (unsigned short)0;
    }

    // --- K staging geometry: 512 16B units/tile; this thread's two units ---
    const int U0 = (w * 2) * 64 + lane, U1 = U0 + 64;
    const int gk0 = (U0 >> 3) * 64 + (((U0 & 7) ^ ((U0 >> 3) & 7)) * 8);
    const int gk1 = (U1 >> 3) * 64 + (((U1 & 7) ^ ((U1 >> 3) & 7)) * 8);
    const int du0 = (w * 2) * 512, du1 = (w * 2 + 1) * 512;   // wave-uniform LDS elem dests

    // --- V staging geometry: thread owns kv pair 2p,2p+1 and d-chunk 8c..8c+7 ---
    const int vp = tid & 31, vc = tid >> 5;
    const long vsrc = (long)(2 * vp) * HS + 8 * vc;

    for (int pass = 0; pass < 2; ++pass) {
        const int qtile = pass ? (15 - bxp) : bxp;
        const int q0  = qtile * 128;
        const int qrb = q0 + w * 32;        // wave's first q-row
        const int NT  = 2 * qtile + 2;      // kv tiles for this q-block

        // Q fragments (scale/log2e folded by rope): aq[qh][khalf]
        bf16x8 aq[2][2];
#pragma unroll
        for (int qh = 0; qh < 2; qh++)
#pragma unroll
            for (int kh = 0; kh < 2; kh++)
                aq[qh][kh] = as_bf(*(const ushortx8*)(Qh + (long)(qrb + qh * 16 + cc) * HS + kh * 32 + grp * 8));

        f32x4 o[2][5];                      // [qh][dt], dt==4 is the rowsum(P) column
#pragma unroll
        for (int qh = 0; qh < 2; qh++)
#pragma unroll
            for (int dt = 0; dt < 5; dt++) o[qh][dt] = (f32x4)0.0f;
        float mr[2][4];
#pragma unroll
        for (int qh = 0; qh < 2; qh++)
#pragma unroll
            for (int j = 0; j < 4; j++) mr[qh][j] = -1e30f;

        // prologue: stage tile 0 (prev pass fully synced by its last barrier;
        // epilogue touches no LDS)
        {
            gload16(Kh + gk0, &Kl[0][du0]);
            gload16(Kh + gk1, &Kl[0][du1]);
            ushortx8 v0 = *(const ushortx8*)(Vh + vsrc);
            ushortx8 v1 = *(const ushortx8*)(Vh + vsrc + HS);
#pragma unroll
            for (int e = 0; e < 8; e++) {
                unsigned int pk = (unsigned int)v0[e] | ((unsigned int)v1[e] << 16);
                *(unsigned int*)&Vt[0][(8 * vc + e) * 72 + 2 * vp] = pk;
            }
        }
        __syncthreads();                    // tile 0 + ones-rows ready

        for (int t = 0; t < NT; ++t) {
            const int cur = t & 1;
            const bool pre = (t + 1 < NT);
            ushortx8 v0, v1;
            if (pre) {                      // issue next tile's loads early (T14)
                const long kofs = (long)(t + 1) * 64 * HS;
                v0 = *(const ushortx8*)(Vh + kofs + vsrc);
                v1 = *(const ushortx8*)(Vh + kofs + vsrc + HS);
                gload16(Kh + kofs + gk0, &Kl[cur ^ 1][du0]);
                gload16(Kh + kofs + gk1, &Kl[cur ^ 1][du1]);
            }
            const int kv0 = t * 64;
            if (kv0 <= qrb + 31) {          // wave-uniform: skip fully-masked tiles
                // --- QK^T ---
                bf16x8 kf[4][2];
#pragma unroll
                for (int ct = 0; ct < 4; ct++)
#pragma unroll
                    for (int kh = 0; kh < 2; kh++)
                        kf[ct][kh] = as_bf(*(const ushortx8*)&Kl[cur][(ct * 16 + cc) * 64 + (((kh * 4 + grp) ^ (cc & 7)) * 8)]);
                f32x4 s[2][4];
                __builtin_amdgcn_s_setprio(1);
#pragma unroll
                for (int qh = 0; qh < 2; qh++)
#pragma unroll
                    for (int ct = 0; ct < 4; ct++) {
                        f32x4 a = (f32x4)0.0f;
                        a = __builtin_amdgcn_mfma_f32_16x16x32_bf16(aq[qh][0], kf[ct][0], a, 0, 0, 0);
                        a = __builtin_amdgcn_mfma_f32_16x16x32_bf16(aq[qh][1], kf[ct][1], a, 0, 0, 0);
                        s[qh][ct] = a;
                    }
                __builtin_amdgcn_s_setprio(0);
                // --- causal mask (diagonal tiles only) ---
                if (kv0 + 63 > qrb) {
#pragma unroll
                    for (int qh = 0; qh < 2; qh++)
#pragma unroll
                        for (int ct = 0; ct < 4; ct++)
#pragma unroll
                            for (int j = 0; j < 4; j++) {
                                int col = kv0 + ct * 16 + cc, row = qrb + qh * 16 + grp * 4 + j;
                                if (col > row) s[qh][ct][j] = -1e30f;
                            }
                }
                // --- online softmax w/ defer-max; denominator via ones-column ---
#pragma unroll
                for (int qh = 0; qh < 2; qh++) {
                    float pm[4];
#pragma unroll
                    for (int j = 0; j < 4; j++) {
                        float v = fmaxf(fmaxf(s[qh][0][j], s[qh][1][j]), fmaxf(s[qh][2][j], s[qh][3][j]));
                        v = fmaxf(v, __shfl_xor(v, 1));
                        v = fmaxf(v, __shfl_xor(v, 2));
                        v = fmaxf(v, __shfl_xor(v, 4));
                        v = fmaxf(v, __shfl_xor(v, 8));
                        pm[j] = v;
                    }
                    bool need = false;
#pragma unroll
                    for (int j = 0; j < 4; j++) need |= (pm[j] > mr[qh][j] + 8.0f);
                    if (__any(need)) {
                        float al[4];
#pragma unroll
                        for (int j = 0; j < 4; j++) {
                            float mn = fmaxf(mr[qh][j], pm[j]);
                            al[j] = exp2f(mr[qh][j] - mn);
                            mr[qh][j] = mn;
                        }
#pragma unroll
                        for (int dt = 0; dt < 5; dt++)
#pragma unroll
                            for (int j = 0; j < 4; j++) o[qh][dt][j] *= al[j];
                    }
#pragma unroll
                    for (int ct = 0; ct < 4; ct++)
#pragma unroll
                        for (int j = 0; j < 4; j++)
                            s[qh][ct][j] = exp2f(s[qh][ct][j] - mr[qh][j]);
                }
                // --- P -> LDS (bf16), re-read as A-fragments (same-wave ordering) ---
#pragma unroll
                for (int qh = 0; qh < 2; qh++)
#pragma unroll
                    for (int ct = 0; ct < 4; ct++)
#pragma unroll
                        for (int j = 0; j < 4; j++)
                            Pl[w][(qh * 16 + grp * 4 + j) * 72 + ct * 16 + cc] = f2bf(s[qh][ct][j]);
                bf16x8 pa[2][2];
#pragma unroll
                for (int qh = 0; qh < 2; qh++)
#pragma unroll
                    for (int kc = 0; kc < 2; kc++)
                        pa[qh][kc] = as_bf(*(ushortx8*)&Pl[w][(qh * 16 + cc) * 72 + kc * 32 + grp * 8]);
                // --- O += P V (dt==4 accumulates rowsum via ones-column) ---
                __builtin_amdgcn_s_setprio(1);
#pragma unroll
                for (int dt = 0; dt < 5; dt++) {
                    bf16x8 vb[2];
#pragma unroll
                    for (int kc = 0; kc < 2; kc++)
                        vb[kc] = as_bf(*(const ushortx8*)&Vt[cur][(dt * 16 + cc) * 72 + kc * 32 + grp * 8]);
#pragma unroll
                    for (int qh = 0; qh < 2; qh++)
#pragma unroll
                        for (int kc = 0; kc < 2; kc++)
                            o[qh][dt] = __builtin_amdgcn_mfma_f32_16x16x32_bf16(pa[qh][kc], vb[kc], o[qh][dt], 0, 0, 0);
                }
                __builtin_amdgcn_s_setprio(0);
            }
            if (pre) {                      // write next V tile (vmcnt waited on v0/v1 use)
#pragma unroll
                for (int e = 0; e < 8; e++) {
                    unsigned int pk = (unsigned int)v0[e] | ((unsigned int)v1[e] << 16);
                    *(unsigned int*)&Vt[cur ^ 1][(8 * vc + e) * 72 + 2 * vp] = pk;
                }
            }
            __syncthreads();                // drains vmcnt (K prefetch) + lgkm; flips buffers
        }

        // epilogue: denominator lives in o[qh][4] at cc==0 lanes
#pragma unroll
        for (int qh = 0; qh < 2; qh++) {
            float inv[4];
#pragma unroll
            for (int j = 0; j < 4; j++) {
                float lrv = __shfl(o[qh][4][j], (lane & 48));   // cc==0 lane of this 16-group
                inv[j] = 1.0f / lrv;
            }
#pragma unroll
            for (int dt = 0; dt < 4; dt++)
#pragma unroll
                for (int j = 0; j < 4; j++) {
                    int row = qrb + qh * 16 + grp * 4 + j;
                    Yb[((long)(b * T_SEQ + row)) * CDIM + h * HS + dt * 16 + cc] = f2bf(o[qh][dt][j] * inv[j]);
                }
        }
    }
}

// ---------------------------------------------------------------- launch
// Workspace: 40 MB. XY 16 (x-bf16, reused as attn-out Y) | Qb 16 | Kb 4 | Vb 4.
extern "C" void kernel_launch(void* const* d_in, const int* in_sizes, int n_in,
                              void* d_out, int out_size, void* d_ws, size_t ws_size,
                              hipStream_t stream) {
    const float* x      = (const float*)d_in[0];
    const float* cosT   = (const float*)d_in[1];
    const float* sinT   = (const float*)d_in[2];
    const float* attn_w = (const float*)d_in[3];
    const float* attn_b = (const float*)d_in[4];
    const float* proj_w = (const float*)d_in[5];
    const float* proj_b = (const float*)d_in[6];
    float* out = (float*)d_out;

    char* p = (char*)d_ws;
    unsigned short* XY = (unsigned short*)p; p += (size_t)MROWS * CDIM * 2;            // 16 MB
    unsigned short* Qb = (unsigned short*)p; p += (size_t)BATCH * NH * T_SEQ * HS * 2; // 16 MB
    unsigned short* Kb = (unsigned short*)p; p += (size_t)BATCH * NG * T_SEQ * HS * 2; //  4 MB
    unsigned short* Vb = (unsigned short*)p; p += (size_t)BATCH * NG * T_SEQ * HS * 2; //  4 MB

    // 1) convert x -> bf16
    f2bf_vec<<<(MROWS * CDIM / 4 + 255) / 256, 256, 0, stream>>>(x, XY, MROWS * CDIM / 4);

    // 2) QKV GEMM (+bias) -> per-head Q/K/V
    gemm_bt<0><<<dim3(NQKV / 128, MROWS / 128), 256, 0, stream>>>(
        XY, attn_w, attn_b, MROWS, NQKV, CDIM, nullptr, Qb, Kb, Vb);

    // 3) RoPE in place (Q also gets 0.125*log2e folded)
    {
        long npairs = (long)BATCH * NH * T_SEQ * 32 + (long)BATCH * NG * T_SEQ * 32;
        rope_kernel<<<(int)((npairs + 255) / 256), 256, 0, stream>>>(Qb, Kb, cosT, sinT);
    }

    // 4) flash attention -> Y (reuses XY region); 512 balanced blocks
    attn_kernel<<<dim3((T_SEQ / 128 / 2) * NH * BATCH), 256, 0, stream>>>(Qb, Kb, Vb, XY);

    // 5) out proj (+bias) -> fp32 out
    gemm_bt<1><<<dim3(CDIM / 128, MROWS / 128), 256, 0, stream>>>(
        XY, proj_w, proj_b, MROWS, CDIM, CDIM, out, nullptr, nullptr, nullptr);
}

// Round 10
// 396.957 us; speedup vs baseline: 1.3930x; 1.0069x over previous
//
#include <hip/hip_runtime.h>

#define T_SEQ 2048
#define CDIM  2048
#define NH    32
#define NG    8
#define HS    64
#define NQKV  3072      // (NH + 2*NG) * HS
#define MROWS 4096      // B * T
#define BATCH 2

typedef __bf16          bf16x8  __attribute__((ext_vector_type(8)));
typedef float           f32x4   __attribute__((ext_vector_type(4)));
typedef unsigned short  ushortx8 __attribute__((ext_vector_type(8)));
typedef unsigned short  ushortx4 __attribute__((ext_vector_type(4)));

__device__ __forceinline__ unsigned short f2bf(float f) {
    unsigned int u = __float_as_uint(f);
    u += 0x7fffu + ((u >> 16) & 1u);          // round-to-nearest-even
    return (unsigned short)(u >> 16);
}
__device__ __forceinline__ float bf2f(unsigned short h) {
    return __uint_as_float(((unsigned int)h) << 16);
}
__device__ __forceinline__ bf16x8 as_bf(ushortx8 u) {
    return __builtin_bit_cast(bf16x8, u);
}
// Async global->LDS, 16B per lane. LDS dest = wave-uniform base + lane*16;
// global source is per-lane (m173) -> swizzled layouts via pre-swizzled source.
__device__ __forceinline__ void gload16(const void* g, void* l) {
    __builtin_amdgcn_global_load_lds(
        (const __attribute__((address_space(1))) unsigned int*)g,
        (__attribute__((address_space(3))) unsigned int*)l, 16, 0, 0);
}

// ---------------------------------------------------------------- converts
__global__ void f2bf_vec(const float* __restrict__ in, unsigned short* __restrict__ out, int n4) {
    int i = blockIdx.x * blockDim.x + threadIdx.x;
    if (i < n4) {
        float4 v = ((const float4*)in)[i];
        ushortx4 o;
        o[0] = f2bf(v.x); o[1] = f2bf(v.y); o[2] = f2bf(v.z); o[3] = f2bf(v.w);
        ((ushortx4*)out)[i] = o;
    }
}

// ---------------------------------------------------------------- GEMM  C = A * Bt^T (+bias)
// A: [M][K] bf16 row-major, staged via global_load_lds with XOR-swizzled
//    per-lane global source (unit u of row r holds chunk u^(r&3)); fragment
//    read at row*32 + ((grp^(cc&3))*8) is bank-uniform (structural minimum).
// B: BBF=1 -> bf16 [N][K], staged identically to A (m97 structure both sides).
//    BBF=0 -> fp32 [N][K], reg-loaded (hoisted), converted, stored stride-48.
// MODE 0: scatter epilogue into Qb/Kb/Vb per-head layout (bias fused)
// MODE 1: fp32 linear output (bias fused)
template<int MODE, int BBF>
__global__ __launch_bounds__(256)
void gemm_bt(const unsigned short* __restrict__ A,
             const unsigned short* __restrict__ Btb, const float* __restrict__ Btf,
             const float* __restrict__ bias, int M, int N, int K,
             float* __restrict__ Cout,
             unsigned short* __restrict__ Qb, unsigned short* __restrict__ Kb,
             unsigned short* __restrict__ Vb) {
    const int tid  = threadIdx.x;
    const int lane = tid & 63, w = tid >> 6;
    const int grp  = lane >> 4, cc = lane & 15;
    const int wm   = w >> 1, wn = w & 1;
    const int m0   = blockIdx.y * 128, n0 = blockIdx.x * 128;

    __shared__ unsigned short Al[128 * 32];     // 8 KB, XOR-unit layout
    __shared__ unsigned short Bl[128 * 48];     // stride 32 (BBF) or 48 (fp32)

    f32x4 acc[4][4];
#pragma unroll
    for (int i = 0; i < 4; i++)
#pragma unroll
        for (int j = 0; j < 4; j++) acc[i][j] = (f32x4)0.0f;

    // --- A staging geometry: tile 128x32 bf16 = 512 16B-units; 2 units/thread ---
    const int U0 = w * 128 + lane, U1 = U0 + 64;
    const int ar0 = U0 >> 2, ac0 = ((U0 & 3) ^ (ar0 & 3)) * 8;
    const int ar1 = U1 >> 2, ac1 = ((U1 & 3) ^ (ar1 & 3)) * 8;
    const unsigned short* as0 = A + (long)(m0 + ar0) * K + ac0;
    const unsigned short* as1 = A + (long)(m0 + ar1) * K + ac1;
    unsigned short* ad0 = Al + w * 1024;        // wave-uniform LDS elem dests
    unsigned short* ad1 = Al + w * 1024 + 512;

    // --- B staging geometry (BBF path mirrors A on n0) ---
    const unsigned short* bsv0 = nullptr; const unsigned short* bsv1 = nullptr;
    unsigned short* bd0 = nullptr; unsigned short* bd1 = nullptr;
    if (BBF) {
        bsv0 = Btb + (long)(n0 + ar0) * K + ac0;
        bsv1 = Btb + (long)(n0 + ar1) * K + ac1;
        bd0 = Bl + w * 1024; bd1 = Bl + w * 1024 + 512;
    }
    const int r0 = tid >> 2;            // fp32 path: 0..63
    const int k8 = (tid & 3) * 8;       // 0,8,16,24

    for (int k0 = 0; k0 < K; k0 += 32) {
        if (BBF) {
            __syncthreads();            // prev compute done reading LDS
            gload16(as0 + k0, ad0); gload16(as1 + k0, ad1);
            gload16(bsv0 + k0, bd0); gload16(bsv1 + k0, bd1);
            __syncthreads();            // vmcnt drained -> tile ready
        } else {
            const float* bp0 = Btf + (long)(n0 + r0)      * K + k0 + k8;
            const float* bp1 = Btf + (long)(n0 + 64 + r0) * K + k0 + k8;
            float4 b0a = *(const float4*)bp0, b0b = *(const float4*)(bp0 + 4);
            float4 b1a = *(const float4*)bp1, b1b = *(const float4*)(bp1 + 4);
            ushortx8 bv0, bv1;
            bv0[0] = f2bf(b0a.x); bv0[1] = f2bf(b0a.y); bv0[2] = f2bf(b0a.z); bv0[3] = f2bf(b0a.w);
            bv0[4] = f2bf(b0b.x); bv0[5] = f2bf(b0b.y); bv0[6] = f2bf(b0b.z); bv0[7] = f2bf(b0b.w);
            bv1[0] = f2bf(b1a.x); bv1[1] = f2bf(b1a.y); bv1[2] = f2bf(b1a.z); bv1[3] = f2bf(b1a.w);
            bv1[4] = f2bf(b1b.x); bv1[5] = f2bf(b1b.y); bv1[6] = f2bf(b1b.z); bv1[7] = f2bf(b1b.w);
            __syncthreads();            // prev compute done
            *(ushortx8*)(Bl + r0 * 48 + k8)        = bv0;
            *(ushortx8*)(Bl + (64 + r0) * 48 + k8) = bv1;
            gload16(as0 + k0, ad0); gload16(as1 + k0, ad1);
            __syncthreads();            // vmcnt + lgkm drained
        }

        bf16x8 af[4], bfr[4];
#pragma unroll
        for (int mi = 0; mi < 4; mi++) {
            const int row = wm * 64 + mi * 16 + cc;
            af[mi] = as_bf(*(ushortx8*)(Al + row * 32 + ((grp ^ (cc & 3)) * 8)));
        }
#pragma unroll
        for (int ni = 0; ni < 4; ni++) {
            const int row = wn * 64 + ni * 16 + cc;
            bfr[ni] = BBF ? as_bf(*(ushortx8*)(Bl + row * 32 + ((grp ^ (cc & 3)) * 8)))
                          : as_bf(*(ushortx8*)(Bl + row * 48 + grp * 8));
        }
#pragma unroll
        for (int mi = 0; mi < 4; mi++)
#pragma unroll
            for (int ni = 0; ni < 4; ni++)
                acc[mi][ni] = __builtin_amdgcn_mfma_f32_16x16x32_bf16(af[mi], bfr[ni], acc[mi][ni], 0, 0, 0);
    }

    if (MODE == 1) {
#pragma unroll
        for (int ni = 0; ni < 4; ni++) {
            const int col = n0 + wn * 64 + ni * 16 + cc;
            const float bb = bias[col];
#pragma unroll
            for (int mi = 0; mi < 4; mi++) {
                const int row = m0 + wm * 64 + mi * 16 + grp * 4;
#pragma unroll
                for (int j = 0; j < 4; j++)
                    Cout[(long)(row + j) * N + col] = acc[mi][ni][j] + bb;
            }
        }
    } else {
        const int slot = (n0 + wn * 64) >> 6;   // 0..47 ; all 64 wave cols share (g,s)
        const int g = slot / 6, s = slot % 6;
        const int b = m0 >> 11;                 // m0 / T_SEQ
        const int t0 = (m0 & (T_SEQ - 1)) + wm * 64;
        unsigned short* dst;
        if (s < 4)        dst = Qb + (long)((b * NH + g * 4 + s) * T_SEQ) * HS;
        else if (s == 4)  dst = Kb + (long)((b * NG + g) * T_SEQ) * HS;
        else              dst = Vb + (long)((b * NG + g) * T_SEQ) * HS;
#pragma unroll
        for (int ni = 0; ni < 4; ni++) {
            const int d = ni * 16 + cc;
            const float bb = bias[slot * 64 + d];
#pragma unroll
            for (int mi = 0; mi < 4; mi++) {
                const int t = t0 + mi * 16 + grp * 4;
#pragma unroll
                for (int j = 0; j < 4; j++)
                    dst[(long)(t + j) * HS + d] = f2bf(acc[mi][ni][j] + bb);
            }
        }
    }
}

// ---------------------------------------------------------------- RoPE (in place, Q gets softmax-scale folded)
__global__ void rope_kernel(unsigned short* __restrict__ Qb, unsigned short* __restrict__ Kb,
                            const float* __restrict__ cosT, const float* __restrict__ sinT) {
    const float QSC = 0.125f * 1.44269504088896340736f;   // 1/sqrt(64) * log2(e)
    long idx = (long)blockIdx.x * blockDim.x + threadIdx.x;
    const long NQP = (long)BATCH * NH * T_SEQ * 32;
    const long NKP = (long)BATCH * NG * T_SEQ * 32;
    unsigned short* base; float sc; long r; int dp;
    if (idx < NQP)            { base = Qb; sc = QSC;  r = idx >> 5;          dp = (int)(idx & 31); }
    else if (idx < NQP + NKP) { long k = idx - NQP; base = Kb; sc = 1.0f; r = k >> 5; dp = (int)(k & 31); }
    else return;
    const int t = (int)(r & (T_SEQ - 1));
    unsigned short* p = base + r * 64;
    float x1 = bf2f(p[dp]), x2 = bf2f(p[dp + 32]);
    float cv = cosT[t * 64 + dp], sv = sinT[t * 64 + dp];
    p[dp]      = f2bf((x1 * cv - x2 * sv) * sc);
    p[dp + 32] = f2bf((x2 * cv + x1 * sv) * sc);
}

// ---------------------------------------------------------------- flash attention (causal, GQA)
// (unchanged from round 8 — 131 us, MfmaUtil 12.5%)
__global__ __launch_bounds__(256, 3)
void attn_kernel(const unsigned short* __restrict__ Qb, const unsigned short* __restrict__ Kb,
                 const unsigned short* __restrict__ Vb, unsigned short* __restrict__ Yb) {
    // T1: bijective XCD swizzle (512 % 8 == 0)
    const int dsp = blockIdx.x;
    const int wk  = (dsp & 7) * 64 + (dsp >> 3);
    const int bxp = wk & 7;
    const int h   = (wk >> 3) & 31;
    const int b   = wk >> 8;

    const int tid = threadIdx.x, lane = tid & 63, w = tid >> 6;
    const int grp = lane >> 4, cc = lane & 15;
    const int g = h >> 2;
    const unsigned short* Qh = Qb + (long)((b * NH + h) * T_SEQ) * HS;
    const unsigned short* Kh = Kb + (long)((b * NG + g) * T_SEQ) * HS;
    const unsigned short* Vh = Vb + (long)((b * NG + g) * T_SEQ) * HS;

    __shared__ unsigned short Kl[2][4096];      // [64 rows][8 units x 8 elems], unit-XOR layout
    __shared__ unsigned short Vt[2][80 * 72];   // transposed: Vt[d][kv], stride 72; d=64..79 static
    __shared__ unsigned short Pl[4][32 * 72];   // per-wave P scratch (stride 72 >= 64!)

    // ones/zeros rows 64..79 (once; never touched by staging)
    for (int i = tid; i < 2 * 16 * 72; i += 256) {
        int buf = i / (16 * 72), rem = i % (16 * 72);
        int r = rem / 72, c = rem % 72;
        Vt[buf][(64 + r) * 72 + c] = (r == 0) ? (unsigned short)0x3F80 : (unsigned short)0;
    }

    // --- K staging geometry: 512 16B units/tile; this thread's two units ---
    const int U0 = (w * 2) * 64 + lane, U1 = U0 + 64;
    const int gk0 = (U0 >> 3) * 64 + (((U0 & 7) ^ ((U0 >> 3) & 7)) * 8);
    const int gk1 = (U1 >> 3) * 64 + (((U1 & 7) ^ ((U1 >> 3) & 7)) * 8);
    const int du0 = (w * 2) * 512, du1 = (w * 2 + 1) * 512;   // wave-uniform LDS elem dests

    // --- V staging geometry: thread owns kv pair 2p,2p+1 and d-chunk 8c..8c+7 ---
    const int vp = tid & 31, vc = tid >> 5;
    const long vsrc = (long)(2 * vp) * HS + 8 * vc;

    for (int pass = 0; pass < 2; ++pass) {
        const int qtile = pass ? (15 - bxp) : bxp;
        const int q0  = qtile * 128;
        const int qrb = q0 + w * 32;        // wave's first q-row
        const int NT  = 2 * qtile + 2;      // kv tiles for this q-block

        // Q fragments (scale/log2e folded by rope): aq[qh][khalf]
        bf16x8 aq[2][2];
#pragma unroll
        for (int qh = 0; qh < 2; qh++)
#pragma unroll
            for (int kh = 0; kh < 2; kh++)
                aq[qh][kh] = as_bf(*(const ushortx8*)(Qh + (long)(qrb + qh * 16 + cc) * HS + kh * 32 + grp * 8));

        f32x4 o[2][5];                      // [qh][dt], dt==4 is the rowsum(P) column
#pragma unroll
        for (int qh = 0; qh < 2; qh++)
#pragma unroll
            for (int dt = 0; dt < 5; dt++) o[qh][dt] = (f32x4)0.0f;
        float mr[2][4];
#pragma unroll
        for (int qh = 0; qh < 2; qh++)
#pragma unroll
            for (int j = 0; j < 4; j++) mr[qh][j] = -1e30f;

        // prologue: stage tile 0 (prev pass fully synced by its last barrier;
        // epilogue touches no LDS)
        {
            gload16(Kh + gk0, &Kl[0][du0]);
            gload16(Kh + gk1, &Kl[0][du1]);
            ushortx8 v0 = *(const ushortx8*)(Vh + vsrc);
            ushortx8 v1 = *(const ushortx8*)(Vh + vsrc + HS);
#pragma unroll
            for (int e = 0; e < 8; e++) {
                unsigned int pk = (unsigned int)v0[e] | ((unsigned int)v1[e] << 16);
                *(unsigned int*)&Vt[0][(8 * vc + e) * 72 + 2 * vp] = pk;
            }
        }
        __syncthreads();                    // tile 0 + ones-rows ready

        for (int t = 0; t < NT; ++t) {
            const int cur = t & 1;
            const bool pre = (t + 1 < NT);
            ushortx8 v0, v1;
            if (pre) {                      // issue next tile's loads early (T14)
                const long kofs = (long)(t + 1) * 64 * HS;
                v0 = *(const ushortx8*)(Vh + kofs + vsrc);
                v1 = *(const ushortx8*)(Vh + kofs + vsrc + HS);
                gload16(Kh + kofs + gk0, &Kl[cur ^ 1][du0]);
                gload16(Kh + kofs + gk1, &Kl[cur ^ 1][du1]);
            }
            const int kv0 = t * 64;
            if (kv0 <= qrb + 31) {          // wave-uniform: skip fully-masked tiles
                // --- QK^T ---
                bf16x8 kf[4][2];
#pragma unroll
                for (int ct = 0; ct < 4; ct++)
#pragma unroll
                    for (int kh = 0; kh < 2; kh++)
                        kf[ct][kh] = as_bf(*(const ushortx8*)&Kl[cur][(ct * 16 + cc) * 64 + (((kh * 4 + grp) ^ (cc & 7)) * 8)]);
                f32x4 s[2][4];
                __builtin_amdgcn_s_setprio(1);
#pragma unroll
                for (int qh = 0; qh < 2; qh++)
#pragma unroll
                    for (int ct = 0; ct < 4; ct++) {
                        f32x4 a = (f32x4)0.0f;
                        a = __builtin_amdgcn_mfma_f32_16x16x32_bf16(aq[qh][0], kf[ct][0], a, 0, 0, 0);
                        a = __builtin_amdgcn_mfma_f32_16x16x32_bf16(aq[qh][1], kf[ct][1], a, 0, 0, 0);
                        s[qh][ct] = a;
                    }
                __builtin_amdgcn_s_setprio(0);
                // --- causal mask (diagonal tiles only) ---
                if (kv0 + 63 > qrb) {
#pragma unroll
                    for (int qh = 0; qh < 2; qh++)
#pragma unroll
                        for (int ct = 0; ct < 4; ct++)
#pragma unroll
                            for (int j = 0; j < 4; j++) {
                                int col = kv0 + ct * 16 + cc, row = qrb + qh * 16 + grp * 4 + j;
                                if (col > row) s[qh][ct][j] = -1e30f;
                            }
                }
                // --- online softmax w/ defer-max; denominator via ones-column ---
#pragma unroll
                for (int qh = 0; qh < 2; qh++) {
                    float pm[4];
#pragma unroll
                    for (int j = 0; j < 4; j++) {
                        float v = fmaxf(fmaxf(s[qh][0][j], s[qh][1][j]), fmaxf(s[qh][2][j], s[qh][3][j]));
                        v = fmaxf(v, __shfl_xor(v, 1));
                        v = fmaxf(v, __shfl_xor(v, 2));
                        v = fmaxf(v, __shfl_xor(v, 4));
                        v = fmaxf(v, __shfl_xor(v, 8));
                        pm[j] = v;
                    }
                    bool need = false;
#pragma unroll
                    for (int j = 0; j < 4; j++) need |= (pm[j] > mr[qh][j] + 8.0f);
                    if (__any(need)) {
                        float al[4];
#pragma unroll
                        for (int j = 0; j < 4; j++) {
                            float mn = fmaxf(mr[qh][j], pm[j]);
                            al[j] = exp2f(mr[qh][j] - mn);
                            mr[qh][j] = mn;
                        }
#pragma unroll
                        for (int dt = 0; dt < 5; dt++)
#pragma unroll
                            for (int j = 0; j < 4; j++) o[qh][dt][j] *= al[j];
                    }
#pragma unroll
                    for (int ct = 0; ct < 4; ct++)
#pragma unroll
                        for (int j = 0; j < 4; j++)
                            s[qh][ct][j] = exp2f(s[qh][ct][j] - mr[qh][j]);
                }
                // --- P -> LDS (bf16), re-read as A-fragments (same-wave ordering) ---
#pragma unroll
                for (int qh = 0; qh < 2; qh++)
#pragma unroll
                    for (int ct = 0; ct < 4; ct++)
#pragma unroll
                        for (int j = 0; j < 4; j++)
                            Pl[w][(qh * 16 + grp * 4 + j) * 72 + ct * 16 + cc] = f2bf(s[qh][ct][j]);
                bf16x8 pa[2][2];
#pragma unroll
                for (int qh = 0; qh < 2; qh++)
#pragma unroll
                    for (int kc = 0; kc < 2; kc++)
                        pa[qh][kc] = as_bf(*(ushortx8*)&Pl[w][(qh * 16 + cc) * 72 + kc * 32 + grp * 8]);
                // --- O += P V (dt==4 accumulates rowsum via ones-column) ---
                __builtin_amdgcn_s_setprio(1);
#pragma unroll
                for (int dt = 0; dt < 5; dt++) {
                    bf16x8 vb[2];
#pragma unroll
                    for (int kc = 0; kc < 2; kc++)
                        vb[kc] = as_bf(*(const ushortx8*)&Vt[cur][(dt * 16 + cc) * 72 + kc * 32 + grp * 8]);
#pragma unroll
                    for (int qh = 0; qh < 2; qh++)
#pragma unroll
                        for (int kc = 0; kc < 2; kc++)
                            o[qh][dt] = __builtin_amdgcn_mfma_f32_16x16x32_bf16(pa[qh][kc], vb[kc], o[qh][dt], 0, 0, 0);
                }
                __builtin_amdgcn_s_setprio(0);
            }
            if (pre) {                      // write next V tile (vmcnt waited on v0/v1 use)
#pragma unroll
                for (int e = 0; e < 8; e++) {
                    unsigned int pk = (unsigned int)v0[e] | ((unsigned int)v1[e] << 16);
                    *(unsigned int*)&Vt[cur ^ 1][(8 * vc + e) * 72 + 2 * vp] = pk;
                }
            }
            __syncthreads();                // drains vmcnt (K prefetch) + lgkm; flips buffers
        }

        // epilogue: denominator lives in o[qh][4] at cc==0 lanes
#pragma unroll
        for (int qh = 0; qh < 2; qh++) {
            float inv[4];
#pragma unroll
            for (int j = 0; j < 4; j++) {
                float lrv = __shfl(o[qh][4][j], (lane & 48));   // cc==0 lane of this 16-group
                inv[j] = 1.0f / lrv;
            }
#pragma unroll
            for (int dt = 0; dt < 4; dt++)
#pragma unroll
                for (int j = 0; j < 4; j++) {
                    int row = qrb + qh * 16 + grp * 4 + j;
                    Yb[((long)(b * T_SEQ + row)) * CDIM + h * HS + dt * 16 + cc] = f2bf(o[qh][dt][j] * inv[j]);
                }
        }
    }
}

// ---------------------------------------------------------------- launch
// Workspace: base 40 MB (XY 16 | Qb 16 | Kb 4 | Vb 4). If ws_size >= 60 MB,
// also stage bf16 weights (Wq 12 | Wp 8) and run the both-bf16 GEMM path
// (global_load_lds both operands). ws_size is constant per session -> the
// branch is graph-capture-safe (same work every call).
extern "C" void kernel_launch(void* const* d_in, const int* in_sizes, int n_in,
                              void* d_out, int out_size, void* d_ws, size_t ws_size,
                              hipStream_t stream) {
    const float* x      = (const float*)d_in[0];
    const float* cosT   = (const float*)d_in[1];
    const float* sinT   = (const float*)d_in[2];
    const float* attn_w = (const float*)d_in[3];
    const float* attn_b = (const float*)d_in[4];
    const float* proj_w = (const float*)d_in[5];
    const float* proj_b = (const float*)d_in[6];
    float* out = (float*)d_out;

    char* p = (char*)d_ws;
    unsigned short* XY = (unsigned short*)p; p += (size_t)MROWS * CDIM * 2;            // 16 MB
    unsigned short* Qb = (unsigned short*)p; p += (size_t)BATCH * NH * T_SEQ * HS * 2; // 16 MB
    unsigned short* Kb = (unsigned short*)p; p += (size_t)BATCH * NG * T_SEQ * HS * 2; //  4 MB
    unsigned short* Vb = (unsigned short*)p; p += (size_t)BATCH * NG * T_SEQ * HS * 2; //  4 MB
    unsigned short* Wq = (unsigned short*)p; p += (size_t)NQKV * CDIM * 2;             // 12 MB
    unsigned short* Wp = (unsigned short*)p; p += (size_t)CDIM * CDIM * 2;             //  8 MB
    const size_t WS_NEED_BF = (size_t)(40 + 12 + 8) * 1024 * 1024;                     // 60 MB
    const bool wbf = (ws_size >= WS_NEED_BF);

    // 1) convert x -> bf16 (and weights, if the bf16-weight path fits)
    f2bf_vec<<<(MROWS * CDIM / 4 + 255) / 256, 256, 0, stream>>>(x, XY, MROWS * CDIM / 4);
    if (wbf) {
        f2bf_vec<<<(NQKV * CDIM / 4 + 255) / 256, 256, 0, stream>>>(attn_w, Wq, NQKV * CDIM / 4);
        f2bf_vec<<<(CDIM * CDIM / 4 + 255) / 256, 256, 0, stream>>>(proj_w, Wp, CDIM * CDIM / 4);
    }

    // 2) QKV GEMM (+bias) -> per-head Q/K/V
    if (wbf)
        gemm_bt<0, 1><<<dim3(NQKV / 128, MROWS / 128), 256, 0, stream>>>(
            XY, Wq, nullptr, attn_b, MROWS, NQKV, CDIM, nullptr, Qb, Kb, Vb);
    else
        gemm_bt<0, 0><<<dim3(NQKV / 128, MROWS / 128), 256, 0, stream>>>(
            XY, nullptr, attn_w, attn_b, MROWS, NQKV, CDIM, nullptr, Qb, Kb, Vb);

    // 3) RoPE in place (Q also gets 0.125*log2e folded)
    {
        long npairs = (long)BATCH * NH * T_SEQ * 32 + (long)BATCH * NG * T_SEQ * 32;
        rope_kernel<<<(int)((npairs + 255) / 256), 256, 0, stream>>>(Qb, Kb, cosT, sinT);
    }

    // 4) flash attention -> Y (reuses XY region); 512 balanced blocks
    attn_kernel<<<dim3((T_SEQ / 128 / 2) * NH * BATCH), 256, 0, stream>>>(Qb, Kb, Vb, XY);

    // 5) out proj (+bias) -> fp32 out
    if (wbf)
        gemm_bt<1, 1><<<dim3(CDIM / 128, MROWS / 128), 256, 0, stream>>>(
            XY, Wp, nullptr, proj_b, MROWS, CDIM, CDIM, out, nullptr, nullptr, nullptr);
    else
        gemm_bt<1, 0><<<dim3(CDIM / 128, MROWS / 128), 256, 0, stream>>>(
            XY, nullptr, proj_w, proj_b, MROWS, CDIM, CDIM, out, nullptr, nullptr, nullptr);
}